// Round 5
// baseline (252.856 us; speedup 1.0000x reference)
//
#include <hip/hip_runtime.h>
#include <hip/hip_bf16.h>
#include <math.h>

#define B_ 2
#define T_ 2048
#define C_ 1024
#define H_ 16
#define HKV_ 4
#define G_ 4
#define HD_ 64
#define KVC_ 256      // HKV*HD
#define NQKV_ 1536    // C_ + 2*KVC_

typedef __attribute__((ext_vector_type(8))) short bf16x8;
typedef __attribute__((ext_vector_type(4))) float f32x4;

static __device__ inline short f2bf(float f) {
    __hip_bfloat16 h = __float2bfloat16(f);
    short s;
    __builtin_memcpy(&s, &h, 2);
    return s;
}
static __device__ inline float bf2f(short s) {
    unsigned int u = ((unsigned int)(unsigned short)s) << 16;
    float f;
    __builtin_memcpy(&f, &u, 4);
    return f;
}

// async global->LDS, 16B per lane; lds base must be wave-uniform.
static __device__ inline void gload_lds16(const short* g, short* lds) {
    __builtin_amdgcn_global_load_lds(
        (const __attribute__((address_space(1))) unsigned int*)g,
        (__attribute__((address_space(3))) unsigned int*)lds, 16, 0, 0);
}

// ---- DPP 16-lane butterfly sum (epilogue only) ----------------------------
template <int CTRL>
static __device__ inline float dpp_mov(float x) {
    int xi = __builtin_bit_cast(int, x);
    int r = __builtin_amdgcn_update_dpp(0, xi, CTRL, 0xF, 0xF, true);
    return __builtin_bit_cast(float, r);
}
static __device__ inline float dpp_sum16(float x) {
    x += dpp_mov<0xB1>(x);    // quad_perm xor1
    x += dpp_mov<0x4E>(x);    // quad_perm xor2
    x += dpp_mov<0x141>(x);   // row_half_mirror
    x += dpp_mov<0x140>(x);   // row_mirror
    return x;
}

// ---------------- elementwise fp32 -> bf16 cast (8 elems/thread) ----------
__global__ __launch_bounds__(256) void cast_bf16(
    const float* __restrict__ in, short* __restrict__ out, int n)
{
    const int i = (blockIdx.x * 256 + threadIdx.x) * 8;
    if (i >= n) return;
    const float4 a = *(const float4*)(in + i);
    const float4 b = *(const float4*)(in + i + 4);
    bf16x8 o;
    o[0] = f2bf(a.x); o[1] = f2bf(a.y); o[2] = f2bf(a.z); o[3] = f2bf(a.w);
    o[4] = f2bf(b.x); o[5] = f2bf(b.y); o[6] = f2bf(b.z); o[7] = f2bf(b.w);
    *(bf16x8*)(out + i) = o;
}

// ---------------- transpose + cast: in[K][N] fp32 -> out[N][K] bf16 -------
__global__ __launch_bounds__(256) void transpose_cast(
    const float* __restrict__ in, short* __restrict__ out, int K, int N)
{
    __shared__ float t[32][33];
    const int tx = threadIdx.x, ty = threadIdx.y;     // 32 x 8
    const int n0 = blockIdx.x * 32, k0 = blockIdx.y * 32;
    #pragma unroll
    for (int j = 0; j < 4; j++)
        t[ty + j * 8][tx] = in[(size_t)(k0 + ty + j * 8) * N + n0 + tx];
    __syncthreads();
    #pragma unroll
    for (int j = 0; j < 4; j++)
        out[(size_t)(n0 + ty + j * 8) * K + k0 + tx] = f2bf(t[tx][ty + j * 8]);
}

// ---------------- bf16 MFMA GEMM: 64x128 tile, BK=32 ----------------------
// C[M,N] = A[M,K] @ Bt[N][K]^T. 4 waves, each 32(m) x 64(n).
template <bool OUT_BF16>
__global__ __launch_bounds__(256) void gemm_bf16(
    const short* __restrict__ A, const short* __restrict__ Bt,
    void* __restrict__ Cout, int M, int N, int K)
{
    __shared__ short As[64 * 32];    // [m][k]
    __shared__ short Bs[128 * 32];   // [n][k]
    const int tid = threadIdx.x;
    const int wave = tid >> 6, lane = tid & 63;
    const int l15 = lane & 15, quad = lane >> 4;
    const int row0 = blockIdx.y * 64, col0 = blockIdx.x * 128;
    const int wrow = (wave >> 1) * 32, wcol = (wave & 1) * 64;

    f32x4 acc[2][4];
    #pragma unroll
    for (int i = 0; i < 2; i++)
        #pragma unroll
        for (int j = 0; j < 4; j++)
            acc[i][j] = (f32x4){0.f, 0.f, 0.f, 0.f};

    for (int kt = 0; kt < K; kt += 32) {
        __syncthreads();
        {   // A: 64 rows, one 1KB chunk per wave
            const int r = wave * 16 + (lane >> 2);
            const int kof = (lane & 3) * 8;
            gload_lds16(A + (size_t)(row0 + r) * K + kt + kof, &As[wave * 512]);
        }
        #pragma unroll
        for (int c2 = 0; c2 < 2; c2++) {   // B: 128 rows, two chunks per wave
            const int c = wave * 2 + c2;
            const int r = c * 16 + (lane >> 2);
            const int kof = (lane & 3) * 8;
            gload_lds16(Bt + (size_t)(col0 + r) * K + kt + kof, &Bs[c * 512]);
        }
        __syncthreads();

        bf16x8 af[2], bf[4];
        #pragma unroll
        for (int mt = 0; mt < 2; mt++)
            af[mt] = *(const bf16x8*)&As[(wrow + mt * 16 + l15) * 32 + quad * 8];
        #pragma unroll
        for (int nt = 0; nt < 4; nt++)
            bf[nt] = *(const bf16x8*)&Bs[(wcol + nt * 16 + l15) * 32 + quad * 8];
        #pragma unroll
        for (int mt = 0; mt < 2; mt++)
            #pragma unroll
            for (int nt = 0; nt < 4; nt++)
                acc[mt][nt] = __builtin_amdgcn_mfma_f32_16x16x32_bf16(
                    af[mt], bf[nt], acc[mt][nt], 0, 0, 0);
    }

    #pragma unroll
    for (int mt = 0; mt < 2; mt++) {
        #pragma unroll
        for (int r = 0; r < 4; r++) {
            const size_t row = row0 + wrow + mt * 16 + quad * 4 + r;
            #pragma unroll
            for (int nt = 0; nt < 4; nt++) {
                const size_t col = col0 + wcol + nt * 16 + l15;
                if (OUT_BF16)
                    ((short*)Cout)[row * N + col] = f2bf(acc[mt][nt][r]);
                else
                    ((float*)Cout)[row * N + col] = acc[mt][nt][r];
            }
        }
    }
}

// ---------------- V tiling prepass ----------------------------------------
// QKV[B*T][1536] V-slice -> Vt[(b*4+kh)*32+jt][64d][64key]
__global__ __launch_bounds__(256) void v_tile(
    const short* __restrict__ QKV, short* __restrict__ Vt)
{
    __shared__ short Ls[64 * 72];
    const int jt = blockIdx.x;         // 0..31
    const int bk = blockIdx.y;         // 0..7 = b*4+kh
    const int b = bk >> 2, kh = bk & 3;
    const int tid = threadIdx.x;
    const int key = tid >> 2, d16 = (tid & 3) * 16;
    const size_t src = (size_t)(b * T_ + jt * 64 + key) * NQKV_ + C_ + KVC_ + kh * 64 + d16;
    const size_t tbase = (size_t)(bk * 32 + jt) * 4096;

    *(bf16x8*)&Ls[key * 72 + d16]     = *(const bf16x8*)(QKV + src);
    *(bf16x8*)&Ls[key * 72 + d16 + 8] = *(const bf16x8*)(QKV + src + 8);
    __syncthreads();
    const int d = tid >> 2, k16 = (tid & 3) * 16;
    bf16x8 o0, o1;
    #pragma unroll
    for (int i = 0; i < 8; i++) o0[i] = Ls[(k16 + i) * 72 + d];
    #pragma unroll
    for (int i = 0; i < 8; i++) o1[i] = Ls[(k16 + 8 + i) * 72 + d];
    *(bf16x8*)(Vt + tbase + d * 64 + k16)     = o0;
    *(bf16x8*)(Vt + tbase + d * 64 + k16 + 8) = o1;
}

// ---------------- barrier-free MFMA flash attention -----------------------
// Q-tile 128 rows (4 waves x 32). K frags direct from QKV (row-major gives
// b128 fragments); V frags from pre-transposed Vtg tiles. Fixed-shift
// softmax (no running max: scores bounded << fp32 exp range; softmax is
// shift-invariant, normalization by l cancels exactly). Only LDS: wave-
// private P round-trip (C-layout -> A-layout), XOR-swizzled conflict-free.
#define LSTR 72   // shorts per P row (144 B, 16B-aligned)

__global__ __launch_bounds__(256, 2) void attn_mfma(
    const short* __restrict__ QKV, const short* __restrict__ Vtg,
    short* __restrict__ Y)
{
    const int qt = (int)gridDim.x - 1 - (int)blockIdx.x;   // longest first
    const int bh = blockIdx.y;
    const int b = bh >> 4, h = bh & 15, kh = h >> 2;
    const float slope = exp2f(-0.5f * (float)(kh + 1));
    const int tid = threadIdx.x;
    const int wave = tid >> 6, lane = tid & 63;
    const int l15 = lane & 15, quad = lane >> 4;

    __shared__ short Ps[4 * 32 * LSTR];   // 18 KB, wave-private 32-row slabs
    short* Pw = &Ps[wave * 32 * LSTR];
    const int wswz = ((quad >> 1) & 1) << 4;   // write-side XOR (row bit3)
    const int rswz = ((l15 >> 3) & 1) << 4;    // read-side  XOR (row bit3)

    const size_t bT = (size_t)b * T_;
    const short* Kbase = QKV + bT * NQKV_ + C_ + kh * 64;
    const size_t tb0 = (size_t)((b * HKV_ + kh) * 32) * 4096;
    const int qrow0w = qt * 128 + wave * 32;

    // Q fragments, softmax scale 1/8 folded in (exact pow2)
    bf16x8 qf[4];   // [mt*2+k0]
    #pragma unroll
    for (int mt = 0; mt < 2; mt++) {
        const short* qp = QKV + (bT + qrow0w + mt * 16 + l15) * NQKV_ + h * 64;
        #pragma unroll
        for (int k0 = 0; k0 < 2; k0++) {
            bf16x8 raw = *(const bf16x8*)(qp + k0 * 32 + quad * 8);
            #pragma unroll
            for (int j = 0; j < 8; j++)
                qf[mt * 2 + k0][j] = f2bf(bf2f(raw[j]) * 0.125f);
        }
    }

    f32x4 Oacc[2][4];
    float psum[8];
    #pragma unroll
    for (int mt = 0; mt < 2; mt++)
        #pragma unroll
        for (int nt = 0; nt < 4; nt++)
            Oacc[mt][nt] = (f32x4){0.f, 0.f, 0.f, 0.f};
    #pragma unroll
    for (int i = 0; i < 8; i++) psum[i] = 0.f;

    const int jmax = 2 * qt + 1;   // tile count = jmax+1 (always even)

    auto loadK = [&](bf16x8 (&kf)[8], int jtk) {
        const short* kp = Kbase + (size_t)(jtk * 64) * NQKV_;
        #pragma unroll
        for (int nt = 0; nt < 4; nt++)
            #pragma unroll
            for (int k0 = 0; k0 < 2; k0++)
                kf[nt * 2 + k0] = *(const bf16x8*)
                    (kp + (size_t)(nt * 16 + l15) * NQKV_ + k0 * 32 + quad * 8);
    };

    auto body = [&](int jtk, bf16x8 (&kf)[8], bf16x8 (&kfn)[8], bool pref) {
        // V fragments for this tile (consumed late -> latency self-hidden)
        bf16x8 vf[8];
        const short* vt = Vtg + tb0 + (size_t)jtk * 4096;
        #pragma unroll
        for (int nt = 0; nt < 4; nt++)
            #pragma unroll
            for (int k0 = 0; k0 < 2; k0++)
                vf[nt * 2 + k0] = *(const bf16x8*)
                    (vt + (nt * 16 + l15) * 64 + k0 * 32 + quad * 8);

        // S = (Q/8) K^T
        f32x4 s[2][4];
        #pragma unroll
        for (int mt = 0; mt < 2; mt++)
            #pragma unroll
            for (int nt = 0; nt < 4; nt++) {
                f32x4 a = {0.f, 0.f, 0.f, 0.f};
                a = __builtin_amdgcn_mfma_f32_16x16x32_bf16(qf[mt*2+0], kf[nt*2+0], a, 0, 0, 0);
                a = __builtin_amdgcn_mfma_f32_16x16x32_bf16(qf[mt*2+1], kf[nt*2+1], a, 0, 0, 0);
                s[mt][nt] = a;
            }

        if (pref) loadK(kfn, jtk + 1);   // K prefetch flies during softmax

        // fixed-shift softmax + ALiBi + causal; P -> wave-private LDS
        const float relf = (float)(jtk * 64 + l15 - quad * 4 - qrow0w);
        const bool diag = (jtk >= 2 * qt);
        #pragma unroll
        for (int mt = 0; mt < 2; mt++) {
            #pragma unroll
            for (int nt = 0; nt < 4; nt++) {
                const int colsw = ((nt * 16 + l15) ^ wswz);
                #pragma unroll
                for (int r = 0; r < 4; r++) {
                    const float relv = relf + (float)(nt * 16 - mt * 16 - r);
                    float p = __expf(fmaf(slope, relv, s[mt][nt][r]));
                    if (diag && relv > 0.f) p = 0.f;
                    psum[mt * 4 + r] += p;
                    Pw[(mt * 16 + quad * 4 + r) * LSTR + colsw] = f2bf(p);
                }
            }
        }
        __asm__ volatile("s_waitcnt lgkmcnt(0)" ::: "memory");

        // O += P @ V
        #pragma unroll
        for (int mt = 0; mt < 2; mt++) {
            const int rbase = (mt * 16 + l15) * LSTR;
            bf16x8 pf0 = *(const bf16x8*)&Pw[rbase + ((quad * 8) ^ rswz)];
            bf16x8 pf1 = *(const bf16x8*)&Pw[rbase + ((32 + quad * 8) ^ rswz)];
            #pragma unroll
            for (int nt = 0; nt < 4; nt++) {
                Oacc[mt][nt] = __builtin_amdgcn_mfma_f32_16x16x32_bf16(
                    pf0, vf[nt*2+0], Oacc[mt][nt], 0, 0, 0);
                Oacc[mt][nt] = __builtin_amdgcn_mfma_f32_16x16x32_bf16(
                    pf1, vf[nt*2+1], Oacc[mt][nt], 0, 0, 0);
            }
        }
    };

    bf16x8 kfA[8], kfB[8];
    loadK(kfA, 0);
    for (int j2 = 0; j2 <= jmax; j2 += 2) {
        body(j2,     kfA, kfB, true);            // j2+1 <= jmax always
        body(j2 + 1, kfB, kfA, j2 + 1 < jmax);
    }

    // epilogue: reduce l across the 16 key-lanes, normalize, store bf16
    #pragma unroll
    for (int mt = 0; mt < 2; mt++) {
        #pragma unroll
        for (int r = 0; r < 4; r++) {
            const float inv = 1.f / dpp_sum16(psum[mt * 4 + r]);
            const int row = qrow0w + mt * 16 + quad * 4 + r;
            short* yp = Y + (bT + row) * C_ + h * 64 + l15;
            #pragma unroll
            for (int nt = 0; nt < 4; nt++)
                yp[nt * 16] = f2bf(Oacc[mt][nt][r] * inv);
        }
    }
}

extern "C" void kernel_launch(void* const* d_in, const int* in_sizes, int n_in,
                              void* d_out, int out_size, void* d_ws, size_t ws_size,
                              hipStream_t stream) {
    const float* x  = (const float*)d_in[0];
    const float* Wq = (const float*)d_in[1];
    const float* Wk = (const float*)d_in[2];
    const float* Wv = (const float*)d_in[3];
    const float* Wo = (const float*)d_in[4];
    float* out = (float*)d_out;

    const int M = B_ * T_;                           // 4096
    short* xb  = (short*)d_ws;                       // [4096][1024]
    short* Wt  = xb  + (size_t)M * C_;               // [1536][1024]
    short* Wot = Wt  + (size_t)NQKV_ * C_;           // [1024][1024]
    short* QKV = Wot + (size_t)C_ * C_;              // [4096][1536]
    short* Yb  = QKV + (size_t)M * NQKV_;            // [4096][1024]
    short* Vtg = Yb  + (size_t)M * C_;               // [8][32][64][64]

    cast_bf16<<<dim3(M * C_ / (256 * 8)), dim3(256), 0, stream>>>(x, xb, M * C_);
    transpose_cast<<<dim3(32, 32), dim3(32, 8), 0, stream>>>(Wq, Wt,                C_, C_);
    transpose_cast<<<dim3(8, 32),  dim3(32, 8), 0, stream>>>(Wk, Wt + C_ * C_,      C_, KVC_);
    transpose_cast<<<dim3(8, 32),  dim3(32, 8), 0, stream>>>(Wv, Wt + (C_+KVC_)*C_, C_, KVC_);
    transpose_cast<<<dim3(32, 32), dim3(32, 8), 0, stream>>>(Wo, Wot,               C_, C_);

    gemm_bf16<true><<<dim3(NQKV_ / 128, M / 64), dim3(256), 0, stream>>>(
        xb, Wt, QKV, M, NQKV_, C_);
    v_tile<<<dim3(32, 8), dim3(256), 0, stream>>>(QKV, Vtg);
    attn_mfma<<<dim3(T_ / 128, B_ * H_), dim3(256), 0, stream>>>(QKV, Vtg, Yb);
    gemm_bf16<false><<<dim3(C_ / 128, M / 64), dim3(256), 0, stream>>>(
        Yb, Wot, out, M, C_, C_);
}

// Round 6
// 208.963 us; speedup vs baseline: 1.2101x; 1.2101x over previous
//
#include <hip/hip_runtime.h>
#include <hip/hip_bf16.h>
#include <math.h>

#define B_ 2
#define T_ 2048
#define C_ 1024
#define H_ 16
#define HKV_ 4
#define G_ 4
#define HD_ 64
#define KVC_ 256      // HKV*HD
#define NQKV_ 1536    // C_ + 2*KVC_

typedef __attribute__((ext_vector_type(8))) short bf16x8;
typedef __attribute__((ext_vector_type(4))) float f32x4;

static __device__ inline short f2bf(float f) {
    __hip_bfloat16 h = __float2bfloat16(f);
    short s;
    __builtin_memcpy(&s, &h, 2);
    return s;
}
static __device__ inline float bf2f(short s) {
    unsigned int u = ((unsigned int)(unsigned short)s) << 16;
    float f;
    __builtin_memcpy(&f, &u, 4);
    return f;
}

// async global->LDS, 16B per lane; lds base wave-uniform, dest = base + lane*16.
static __device__ inline void gload_lds16(const short* g, short* lds) {
    __builtin_amdgcn_global_load_lds(
        (const __attribute__((address_space(1))) unsigned int*)g,
        (__attribute__((address_space(3))) unsigned int*)lds, 16, 0, 0);
}

// ---- DPP 16-lane butterfly sum (epilogue only) ----------------------------
template <int CTRL>
static __device__ inline float dpp_mov(float x) {
    int xi = __builtin_bit_cast(int, x);
    int r = __builtin_amdgcn_update_dpp(0, xi, CTRL, 0xF, 0xF, true);
    return __builtin_bit_cast(float, r);
}
static __device__ inline float dpp_sum16(float x) {
    x += dpp_mov<0xB1>(x);    // quad_perm xor1
    x += dpp_mov<0x4E>(x);    // quad_perm xor2
    x += dpp_mov<0x141>(x);   // row_half_mirror
    x += dpp_mov<0x140>(x);   // row_mirror
    return x;
}

// ---------------- elementwise fp32 -> bf16 cast (8 elems/thread) ----------
__global__ __launch_bounds__(256) void cast_bf16(
    const float* __restrict__ in, short* __restrict__ out, int n)
{
    const int i = (blockIdx.x * 256 + threadIdx.x) * 8;
    if (i >= n) return;
    const float4 a = *(const float4*)(in + i);
    const float4 b = *(const float4*)(in + i + 4);
    bf16x8 o;
    o[0] = f2bf(a.x); o[1] = f2bf(a.y); o[2] = f2bf(a.z); o[3] = f2bf(a.w);
    o[4] = f2bf(b.x); o[5] = f2bf(b.y); o[6] = f2bf(b.z); o[7] = f2bf(b.w);
    *(bf16x8*)(out + i) = o;
}

// ---------------- transpose + cast: in[K][N] fp32 -> out[N][K] bf16 -------
__global__ __launch_bounds__(256) void transpose_cast(
    const float* __restrict__ in, short* __restrict__ out, int K, int N)
{
    __shared__ float t[32][33];
    const int tx = threadIdx.x, ty = threadIdx.y;     // 32 x 8
    const int n0 = blockIdx.x * 32, k0 = blockIdx.y * 32;
    #pragma unroll
    for (int j = 0; j < 4; j++)
        t[ty + j * 8][tx] = in[(size_t)(k0 + ty + j * 8) * N + n0 + tx];
    __syncthreads();
    #pragma unroll
    for (int j = 0; j < 4; j++)
        out[(size_t)(n0 + ty + j * 8) * K + k0 + tx] = f2bf(t[tx][ty + j * 8]);
}

// ---------------- bf16 MFMA GEMM: 64x128 tile, BK=32 ----------------------
template <bool OUT_BF16>
__global__ __launch_bounds__(256) void gemm_bf16(
    const short* __restrict__ A, const short* __restrict__ Bt,
    void* __restrict__ Cout, int M, int N, int K)
{
    __shared__ short As[64 * 32];
    __shared__ short Bs[128 * 32];
    const int tid = threadIdx.x;
    const int wave = tid >> 6, lane = tid & 63;
    const int l15 = lane & 15, quad = lane >> 4;
    const int row0 = blockIdx.y * 64, col0 = blockIdx.x * 128;
    const int wrow = (wave >> 1) * 32, wcol = (wave & 1) * 64;

    f32x4 acc[2][4];
    #pragma unroll
    for (int i = 0; i < 2; i++)
        #pragma unroll
        for (int j = 0; j < 4; j++)
            acc[i][j] = (f32x4){0.f, 0.f, 0.f, 0.f};

    for (int kt = 0; kt < K; kt += 32) {
        __syncthreads();
        {
            const int r = wave * 16 + (lane >> 2);
            const int kof = (lane & 3) * 8;
            gload_lds16(A + (size_t)(row0 + r) * K + kt + kof, &As[wave * 512]);
        }
        #pragma unroll
        for (int c2 = 0; c2 < 2; c2++) {
            const int c = wave * 2 + c2;
            const int r = c * 16 + (lane >> 2);
            const int kof = (lane & 3) * 8;
            gload_lds16(Bt + (size_t)(col0 + r) * K + kt + kof, &Bs[c * 512]);
        }
        __syncthreads();

        bf16x8 af[2], bf[4];
        #pragma unroll
        for (int mt = 0; mt < 2; mt++)
            af[mt] = *(const bf16x8*)&As[(wrow + mt * 16 + l15) * 32 + quad * 8];
        #pragma unroll
        for (int nt = 0; nt < 4; nt++)
            bf[nt] = *(const bf16x8*)&Bs[(wcol + nt * 16 + l15) * 32 + quad * 8];
        #pragma unroll
        for (int mt = 0; mt < 2; mt++)
            #pragma unroll
            for (int nt = 0; nt < 4; nt++)
                acc[mt][nt] = __builtin_amdgcn_mfma_f32_16x16x32_bf16(
                    af[mt], bf[nt], acc[mt][nt], 0, 0, 0);
    }

    #pragma unroll
    for (int mt = 0; mt < 2; mt++) {
        #pragma unroll
        for (int r = 0; r < 4; r++) {
            const size_t row = row0 + wrow + mt * 16 + quad * 4 + r;
            #pragma unroll
            for (int nt = 0; nt < 4; nt++) {
                const size_t col = col0 + wcol + nt * 16 + l15;
                if (OUT_BF16)
                    ((short*)Cout)[row * N + col] = f2bf(acc[mt][nt][r]);
                else
                    ((float*)Cout)[row * N + col] = acc[mt][nt][r];
            }
        }
    }
}

// ---------------- K/V tiling prepass (XOR-swizzled 16B blocks) ------------
// K tile [key][dblk^(key&7)][8] ; V tile [d][kblk^(d&7)][8]. The swizzle
// makes the unpadded [64][64] MFMA fragment reads 2-way-conflict-free while
// staying global_load_lds-compatible (linear lane->LDS mapping).
__global__ __launch_bounds__(256) void kv_tile(
    const short* __restrict__ QKV, short* __restrict__ Kt, short* __restrict__ Vt)
{
    __shared__ short Ls[64 * 72];
    const int jt = blockIdx.x;         // 0..31
    const int bk = blockIdx.y;         // 0..7 = b*4+kh
    const int b = bk >> 2, kh = bk & 3;
    const int tid = threadIdx.x;
    const int key = tid >> 2, d16 = (tid & 3) * 16;
    const size_t src = (size_t)(b * T_ + jt * 64 + key) * NQKV_ + C_ + kh * 64 + d16;
    const size_t tbase = (size_t)(bk * 32 + jt) * 4096;

    {   // K: swizzled tiled copy
        const int db0 = (tid & 3) * 2, db1 = db0 + 1;
        *(bf16x8*)(Kt + tbase + key * 64 + ((db0 ^ (key & 7)) * 8)) =
            *(const bf16x8*)(QKV + src);
        *(bf16x8*)(Kt + tbase + key * 64 + ((db1 ^ (key & 7)) * 8)) =
            *(const bf16x8*)(QKV + src + 8);
    }
    // V: transpose through LDS, swizzled key-blocks
    *(bf16x8*)&Ls[key * 72 + d16]     = *(const bf16x8*)(QKV + src + KVC_);
    *(bf16x8*)&Ls[key * 72 + d16 + 8] = *(const bf16x8*)(QKV + src + KVC_ + 8);
    __syncthreads();
    const int d = tid >> 2, k16 = (tid & 3) * 16;
    bf16x8 o0, o1;
    #pragma unroll
    for (int i = 0; i < 8; i++) o0[i] = Ls[(k16 + i) * 72 + d];
    #pragma unroll
    for (int i = 0; i < 8; i++) o1[i] = Ls[(k16 + 8 + i) * 72 + d];
    const int kb0 = (tid & 3) * 2, kb1 = kb0 + 1;
    *(bf16x8*)(Vt + tbase + d * 64 + ((kb0 ^ (d & 7)) * 8)) = o0;
    *(bf16x8*)(Vt + tbase + d * 64 + ((kb1 ^ (d & 7)) * 8)) = o1;
}

// ---------------- MFMA flash attention ------------------------------------
// 128-row Q-tile, 4 waves x 32 rows. K/V staged per 64-key tile via async
// global_load_lds DMA from pre-swizzled tiles (no staging VALU/DS-writes).
// Fixed-shift softmax (scores bounded; shift-invariance exact). Ps = only
// CPU-side LDS transform (wave-private, XOR-swizzled).
#define LSTR 72

__global__ __launch_bounds__(256) void attn_mfma(
    const short* __restrict__ QKV, const short* __restrict__ Ktg,
    const short* __restrict__ Vtg, short* __restrict__ Y)
{
    const int qt = (int)gridDim.x - 1 - (int)blockIdx.x;   // longest first
    const int bh = blockIdx.y;
    const int b = bh >> 4, h = bh & 15, kh = h >> 2;
    const float slope = exp2f(-0.5f * (float)(kh + 1));
    const int tid = threadIdx.x;
    const int wave = tid >> 6, lane = tid & 63;
    const int l15 = lane & 15, quad = lane >> 4;
    const int lswz = (l15 & 7) * 8;            // frag-read XOR (shorts)

    __shared__ short Ks[4096];                 // [key][dblk^(key&7)][8]
    __shared__ short Vs[4096];                 // [d][kblk^(d&7)][8]
    __shared__ short Ps[128 * LSTR];           // 18.4 KB wave-private slabs
    short* Pw = &Ps[wave * 32 * LSTR];
    const int wswz = ((quad >> 1) & 1) << 4;   // P write XOR (row bit3)
    const int rswz = ((l15 >> 3) & 1) << 4;    // P read  XOR (row bit3)

    const size_t bT = (size_t)b * T_;
    const size_t tb0 = (size_t)((b * HKV_ + kh) * 32) * 4096;
    const int qrow0w = qt * 128 + wave * 32;

    // Q fragments; softmax scale 1/8 folded in (exact pow2)
    bf16x8 qf[4];   // [mt*2+k0]
    #pragma unroll
    for (int mt = 0; mt < 2; mt++) {
        const short* qp = QKV + (bT + qrow0w + mt * 16 + l15) * NQKV_ + h * 64;
        #pragma unroll
        for (int k0 = 0; k0 < 2; k0++) {
            bf16x8 raw = *(const bf16x8*)(qp + k0 * 32 + quad * 8);
            #pragma unroll
            for (int j = 0; j < 8; j++)
                qf[mt * 2 + k0][j] = f2bf(bf2f(raw[j]) * 0.125f);
        }
    }

    f32x4 Oacc[2][4];
    float psum[8];
    #pragma unroll
    for (int mt = 0; mt < 2; mt++)
        #pragma unroll
        for (int nt = 0; nt < 4; nt++)
            Oacc[mt][nt] = (f32x4){0.f, 0.f, 0.f, 0.f};
    #pragma unroll
    for (int i = 0; i < 8; i++) psum[i] = 0.f;

    const int ntile = 2 * qt + 2;

    for (int jtk = 0; jtk < ntile; jtk++) {
        __syncthreads();                       // consumers of prev tile done
        {
            const short* Ktile = Ktg + tb0 + (size_t)jtk * 4096;
            const short* Vtile = Vtg + tb0 + (size_t)jtk * 4096;
            #pragma unroll
            for (int i = 0; i < 2; i++) {
                const int ch = wave * 2 + i;   // 0..7, 1KB chunks
                gload_lds16(Ktile + ch * 512 + lane * 8, &Ks[ch * 512]);
                gload_lds16(Vtile + ch * 512 + lane * 8, &Vs[ch * 512]);
            }
        }
        __syncthreads();                       // DMA drained by barrier

        // S = (Q/8) K^T  (K frag: B[k=d][n=key], swizzled block read)
        f32x4 s[2][4];
        #pragma unroll
        for (int nt = 0; nt < 4; nt++) {
            bf16x8 kf0 = *(const bf16x8*)&Ks[(nt * 16 + l15) * 64 + (((0 * 4 + quad) * 8) ^ lswz)];
            bf16x8 kf1 = *(const bf16x8*)&Ks[(nt * 16 + l15) * 64 + (((1 * 4 + quad) * 8) ^ lswz)];
            #pragma unroll
            for (int mt = 0; mt < 2; mt++) {
                f32x4 a = (mt == 0 && false) ? s[0][0] : (f32x4){0.f, 0.f, 0.f, 0.f};
                a = __builtin_amdgcn_mfma_f32_16x16x32_bf16(qf[mt * 2 + 0], kf0, a, 0, 0, 0);
                a = __builtin_amdgcn_mfma_f32_16x16x32_bf16(qf[mt * 2 + 1], kf1, a, 0, 0, 0);
                s[mt][nt] = a;
            }
        }

        // fixed-shift softmax + ALiBi + causal; P -> wave-private LDS
        const float relf = (float)(jtk * 64 + l15 - quad * 4 - qrow0w);
        const bool maskt = (jtk >= 2 * qt);    // only last two tiles can cross
        #pragma unroll
        for (int mt = 0; mt < 2; mt++) {
            #pragma unroll
            for (int nt = 0; nt < 4; nt++) {
                const int colsw = ((nt * 16 + l15) ^ wswz);
                #pragma unroll
                for (int r = 0; r < 4; r++) {
                    const float relv = relf + (float)(nt * 16 - mt * 16 - r);
                    float p = __expf(fmaf(slope, relv, s[mt][nt][r]));
                    if (maskt && relv > 0.f) p = 0.f;
                    psum[mt * 4 + r] += p;
                    Pw[(mt * 16 + quad * 4 + r) * LSTR + colsw] = f2bf(p);
                }
            }
        }
        __asm__ volatile("s_waitcnt lgkmcnt(0)" ::: "memory");

        // O += P @ V  (V frag: B[k=key][n=d], swizzled block read)
        #pragma unroll
        for (int mt = 0; mt < 2; mt++) {
            const int rbase = (mt * 16 + l15) * LSTR;
            bf16x8 pf0 = *(const bf16x8*)&Pw[rbase + ((quad * 8) ^ rswz)];
            bf16x8 pf1 = *(const bf16x8*)&Pw[rbase + ((32 + quad * 8) ^ rswz)];
            #pragma unroll
            for (int nt = 0; nt < 4; nt++) {
                bf16x8 vf0 = *(const bf16x8*)&Vs[(nt * 16 + l15) * 64 + (((0 * 4 + quad) * 8) ^ lswz)];
                bf16x8 vf1 = *(const bf16x8*)&Vs[(nt * 16 + l15) * 64 + (((1 * 4 + quad) * 8) ^ lswz)];
                Oacc[mt][nt] = __builtin_amdgcn_mfma_f32_16x16x32_bf16(
                    pf0, vf0, Oacc[mt][nt], 0, 0, 0);
                Oacc[mt][nt] = __builtin_amdgcn_mfma_f32_16x16x32_bf16(
                    pf1, vf1, Oacc[mt][nt], 0, 0, 0);
            }
        }
    }

    // epilogue: reduce l across the 16 key-lanes, normalize, store bf16
    #pragma unroll
    for (int mt = 0; mt < 2; mt++) {
        #pragma unroll
        for (int r = 0; r < 4; r++) {
            const float inv = 1.f / dpp_sum16(psum[mt * 4 + r]);
            const int row = qrow0w + mt * 16 + quad * 4 + r;
            short* yp = Y + (bT + row) * C_ + h * 64 + l15;
            #pragma unroll
            for (int nt = 0; nt < 4; nt++)
                yp[nt * 16] = f2bf(Oacc[mt][nt][r] * inv);
        }
    }
}

extern "C" void kernel_launch(void* const* d_in, const int* in_sizes, int n_in,
                              void* d_out, int out_size, void* d_ws, size_t ws_size,
                              hipStream_t stream) {
    const float* x  = (const float*)d_in[0];
    const float* Wq = (const float*)d_in[1];
    const float* Wk = (const float*)d_in[2];
    const float* Wv = (const float*)d_in[3];
    const float* Wo = (const float*)d_in[4];
    float* out = (float*)d_out;

    const int M = B_ * T_;                           // 4096
    short* xb  = (short*)d_ws;                       // [4096][1024]
    short* Wt  = xb  + (size_t)M * C_;               // [1536][1024]
    short* Wot = Wt  + (size_t)NQKV_ * C_;           // [1024][1024]
    short* QKV = Wot + (size_t)C_ * C_;              // [4096][1536]
    short* Yb  = QKV + (size_t)M * NQKV_;            // [4096][1024]
    short* Ktg = Yb  + (size_t)M * C_;               // [8][32][4096] swizzled
    short* Vtg = Ktg + (size_t)8 * 32 * 4096;        // [8][32][4096] swizzled

    cast_bf16<<<dim3(M * C_ / (256 * 8)), dim3(256), 0, stream>>>(x, xb, M * C_);
    transpose_cast<<<dim3(32, 32), dim3(32, 8), 0, stream>>>(Wq, Wt,                C_, C_);
    transpose_cast<<<dim3(8, 32),  dim3(32, 8), 0, stream>>>(Wk, Wt + C_ * C_,      C_, KVC_);
    transpose_cast<<<dim3(8, 32),  dim3(32, 8), 0, stream>>>(Wv, Wt + (C_+KVC_)*C_, C_, KVC_);
    transpose_cast<<<dim3(32, 32), dim3(32, 8), 0, stream>>>(Wo, Wot,               C_, C_);

    gemm_bf16<true><<<dim3(NQKV_ / 128, M / 64), dim3(256), 0, stream>>>(
        xb, Wt, QKV, M, NQKV_, C_);
    kv_tile<<<dim3(32, 8), dim3(256), 0, stream>>>(QKV, Ktg, Vtg);
    attn_mfma<<<dim3(T_ / 128, B_ * H_), dim3(256), 0, stream>>>(QKV, Ktg, Vtg, Yb);
    gemm_bf16<false><<<dim3(C_ / 128, M / 64), dim3(256), 0, stream>>>(
        Yb, Wot, out, M, C_, C_);
}

// Round 7
// 182.169 us; speedup vs baseline: 1.3880x; 1.1471x over previous
//
#include <hip/hip_runtime.h>
#include <hip/hip_bf16.h>
#include <math.h>

#define B_ 2
#define T_ 2048
#define C_ 1024
#define H_ 16
#define HKV_ 4
#define G_ 4
#define HD_ 64
#define KVC_ 256      // HKV*HD
#define NQKV_ 1536    // C_ + 2*KVC_
#define NQT_ 32       // T_/64 q-tiles

typedef __attribute__((ext_vector_type(8))) short bf16x8;
typedef __attribute__((ext_vector_type(4))) float f32x4;

static __device__ inline short f2bf(float f) {
    __hip_bfloat16 h = __float2bfloat16(f);
    short s;
    __builtin_memcpy(&s, &h, 2);
    return s;
}
static __device__ inline float bf2f(short s) {
    unsigned int u = ((unsigned int)(unsigned short)s) << 16;
    float f;
    __builtin_memcpy(&f, &u, 4);
    return f;
}

// async global->LDS, 16B per lane; lds base wave-uniform, dest = base + lane*16.
static __device__ inline void gload_lds16(const short* g, short* lds) {
    __builtin_amdgcn_global_load_lds(
        (const __attribute__((address_space(1))) unsigned int*)g,
        (__attribute__((address_space(3))) unsigned int*)lds, 16, 0, 0);
}

// ---- DPP 16-lane butterfly sum (epilogue only) ----------------------------
template <int CTRL>
static __device__ inline float dpp_mov(float x) {
    int xi = __builtin_bit_cast(int, x);
    int r = __builtin_amdgcn_update_dpp(0, xi, CTRL, 0xF, 0xF, true);
    return __builtin_bit_cast(float, r);
}
static __device__ inline float dpp_sum16(float x) {
    x += dpp_mov<0xB1>(x);    // quad_perm xor1
    x += dpp_mov<0x4E>(x);    // quad_perm xor2
    x += dpp_mov<0x141>(x);   // row_half_mirror
    x += dpp_mov<0x140>(x);   // row_mirror
    return x;
}

// ---------------- elementwise fp32 -> bf16 cast (8 elems/thread) ----------
__global__ __launch_bounds__(256) void cast_bf16(
    const float* __restrict__ in, short* __restrict__ out, int n)
{
    const int i = (blockIdx.x * 256 + threadIdx.x) * 8;
    if (i >= n) return;
    const float4 a = *(const float4*)(in + i);
    const float4 b = *(const float4*)(in + i + 4);
    bf16x8 o;
    o[0] = f2bf(a.x); o[1] = f2bf(a.y); o[2] = f2bf(a.z); o[3] = f2bf(a.w);
    o[4] = f2bf(b.x); o[5] = f2bf(b.y); o[6] = f2bf(b.z); o[7] = f2bf(b.w);
    *(bf16x8*)(out + i) = o;
}

// ------------- fused weight transpose+cast (z selects matrix) -------------
// in[K][N] fp32 -> out[N][K] bf16 ; z: 0=Wq 1=Wk 2=Wv 3=Wo
__global__ __launch_bounds__(256) void w_transpose(
    const float* __restrict__ Wq, const float* __restrict__ Wk,
    const float* __restrict__ Wv, const float* __restrict__ Wo,
    short* __restrict__ Wt, short* __restrict__ Wot)
{
    const int z = blockIdx.z;
    const float* in;
    short* out;
    int N;
    if (z == 0)      { in = Wq; out = Wt;                     N = C_; }
    else if (z == 1) { in = Wk; out = Wt + C_ * C_;           N = KVC_; }
    else if (z == 2) { in = Wv; out = Wt + (C_ + KVC_) * C_;  N = KVC_; }
    else             { in = Wo; out = Wot;                    N = C_; }
    const int n0 = blockIdx.x * 32;
    if (n0 >= N) return;
    __shared__ float t[32][33];
    const int tx = threadIdx.x, ty = threadIdx.y;     // 32 x 8
    const int k0 = blockIdx.y * 32;
    #pragma unroll
    for (int j = 0; j < 4; j++)
        t[ty + j * 8][tx] = in[(size_t)(k0 + ty + j * 8) * N + n0 + tx];
    __syncthreads();
    #pragma unroll
    for (int j = 0; j < 4; j++)
        out[(size_t)(n0 + ty + j * 8) * C_ + k0 + tx] = f2bf(t[tx][ty + j * 8]);
}

// ---------------- bf16 MFMA GEMM: 64x128 tile, BK=32 ----------------------
template <bool OUT_BF16>
__global__ __launch_bounds__(256) void gemm_bf16(
    const short* __restrict__ A, const short* __restrict__ Bt,
    void* __restrict__ Cout, int M, int N, int K)
{
    __shared__ short As[64 * 32];
    __shared__ short Bs[128 * 32];
    const int tid = threadIdx.x;
    const int wave = tid >> 6, lane = tid & 63;
    const int l15 = lane & 15, quad = lane >> 4;
    const int row0 = blockIdx.y * 64, col0 = blockIdx.x * 128;
    const int wrow = (wave >> 1) * 32, wcol = (wave & 1) * 64;

    f32x4 acc[2][4];
    #pragma unroll
    for (int i = 0; i < 2; i++)
        #pragma unroll
        for (int j = 0; j < 4; j++)
            acc[i][j] = (f32x4){0.f, 0.f, 0.f, 0.f};

    for (int kt = 0; kt < K; kt += 32) {
        __syncthreads();
        {
            const int r = wave * 16 + (lane >> 2);
            const int kof = (lane & 3) * 8;
            gload_lds16(A + (size_t)(row0 + r) * K + kt + kof, &As[wave * 512]);
        }
        #pragma unroll
        for (int c2 = 0; c2 < 2; c2++) {
            const int c = wave * 2 + c2;
            const int r = c * 16 + (lane >> 2);
            const int kof = (lane & 3) * 8;
            gload_lds16(Bt + (size_t)(col0 + r) * K + kt + kof, &Bs[c * 512]);
        }
        __syncthreads();

        bf16x8 af[2], bf[4];
        #pragma unroll
        for (int mt = 0; mt < 2; mt++)
            af[mt] = *(const bf16x8*)&As[(wrow + mt * 16 + l15) * 32 + quad * 8];
        #pragma unroll
        for (int nt = 0; nt < 4; nt++)
            bf[nt] = *(const bf16x8*)&Bs[(wcol + nt * 16 + l15) * 32 + quad * 8];
        #pragma unroll
        for (int mt = 0; mt < 2; mt++)
            #pragma unroll
            for (int nt = 0; nt < 4; nt++)
                acc[mt][nt] = __builtin_amdgcn_mfma_f32_16x16x32_bf16(
                    af[mt], bf[nt], acc[mt][nt], 0, 0, 0);
    }

    #pragma unroll
    for (int mt = 0; mt < 2; mt++) {
        #pragma unroll
        for (int r = 0; r < 4; r++) {
            const size_t row = row0 + wrow + mt * 16 + quad * 4 + r;
            #pragma unroll
            for (int nt = 0; nt < 4; nt++) {
                const size_t col = col0 + wcol + nt * 16 + l15;
                if (OUT_BF16)
                    ((short*)Cout)[row * N + col] = f2bf(acc[mt][nt][r]);
                else
                    ((float*)Cout)[row * N + col] = acc[mt][nt][r];
            }
        }
    }
}

// ---------------- K/V tiling prepass (XOR-swizzled 16B blocks) ------------
// K tile [key][dblk^(key&7)][8] ; V tile [d][kblk^(d&7)][8].
__global__ __launch_bounds__(256) void kv_tile(
    const short* __restrict__ QKV, short* __restrict__ Kt, short* __restrict__ Vt)
{
    __shared__ short Ls[64 * 72];
    const int jt = blockIdx.x;         // 0..31
    const int bk = blockIdx.y;         // 0..7 = b*4+kh
    const int b = bk >> 2, kh = bk & 3;
    const int tid = threadIdx.x;
    const int key = tid >> 2, d16 = (tid & 3) * 16;
    const size_t src = (size_t)(b * T_ + jt * 64 + key) * NQKV_ + C_ + kh * 64 + d16;
    const size_t tbase = (size_t)(bk * 32 + jt) * 4096;

    {   // K: swizzled tiled copy
        const int db0 = (tid & 3) * 2, db1 = db0 + 1;
        *(bf16x8*)(Kt + tbase + key * 64 + ((db0 ^ (key & 7)) * 8)) =
            *(const bf16x8*)(QKV + src);
        *(bf16x8*)(Kt + tbase + key * 64 + ((db1 ^ (key & 7)) * 8)) =
            *(const bf16x8*)(QKV + src + 8);
    }
    // V: transpose through LDS, swizzled key-blocks
    *(bf16x8*)&Ls[key * 72 + d16]     = *(const bf16x8*)(QKV + src + KVC_);
    *(bf16x8*)&Ls[key * 72 + d16 + 8] = *(const bf16x8*)(QKV + src + KVC_ + 8);
    __syncthreads();
    const int d = tid >> 2, k16 = (tid & 3) * 16;
    bf16x8 o0, o1;
    #pragma unroll
    for (int i = 0; i < 8; i++) o0[i] = Ls[(k16 + i) * 72 + d];
    #pragma unroll
    for (int i = 0; i < 8; i++) o1[i] = Ls[(k16 + 8 + i) * 72 + d];
    const int kb0 = (tid & 3) * 2, kb1 = kb0 + 1;
    *(bf16x8*)(Vt + tbase + d * 64 + ((kb0 ^ (d & 7)) * 8)) = o0;
    *(bf16x8*)(Vt + tbase + d * 64 + ((kb1 ^ (d & 7)) * 8)) = o1;
}

// ---------------- MFMA flash attention, work-balanced pairing -------------
// Block (qx,bh) owns TWO 64-row Q-tiles: qt_lo=qx, qt_hi=31-qx. lo's key
// tiles are a prefix of hi's, so one K/V stream + one set of K/V fragment
// reads serves both. Per-block compute = qt_lo+qt_hi+2 = 33 tiles: constant
// -> no CU load imbalance. 4 waves x 16 Q-rows per tile. DMA-staged K/V
// (pre-swizzled tiles), fixed-shift softmax, wave-private swizzled Ps.
#define LSTR 72

__global__ __launch_bounds__(256) void attn_mfma(
    const short* __restrict__ QKV, const short* __restrict__ Ktg,
    const short* __restrict__ Vtg, short* __restrict__ Y)
{
    const int qx = blockIdx.x;                 // 0..15
    const int bh = blockIdx.y;
    const int qtL = qx, qtH = NQT_ - 1 - qx;   // pair sums to 31
    const int b = bh >> 4, h = bh & 15, kh = h >> 2;
    const float slope = exp2f(-0.5f * (float)(kh + 1));
    const int tid = threadIdx.x;
    const int wave = tid >> 6, lane = tid & 63;
    const int l15 = lane & 15, quad = lane >> 4;
    const int lswz = (l15 & 7) * 8;            // K/V frag-read XOR (shorts)

    __shared__ short Ks[4096];                 // [key][dblk^(key&7)][8]
    __shared__ short Vs[4096];                 // [d][kblk^(d&7)][8]
    __shared__ short Ps[4 * 32 * LSTR];        // per wave: rows 0-15 hi, 16-31 lo
    short* Pw = &Ps[wave * 32 * LSTR];
    const int wswz = ((quad >> 1) & 1) << 4;   // P write XOR (row bit3)
    const int rswz = ((l15 >> 3) & 1) << 4;    // P read  XOR (row bit3)

    const size_t bT = (size_t)b * T_;
    const size_t tb0 = (size_t)((b * HKV_ + kh) * 32) * 4096;
    const int qrow0H = qtH * 64 + wave * 16;
    const int qrow0L = qtL * 64 + wave * 16;

    // Q fragments for both tiles; softmax scale 1/8 folded in (exact pow2)
    bf16x8 qfH[2], qfL[2];
    #pragma unroll
    for (int k0 = 0; k0 < 2; k0++) {
        const short* qpH = QKV + (bT + qrow0H + l15) * NQKV_ + h * 64;
        const short* qpL = QKV + (bT + qrow0L + l15) * NQKV_ + h * 64;
        bf16x8 rH = *(const bf16x8*)(qpH + k0 * 32 + quad * 8);
        bf16x8 rL = *(const bf16x8*)(qpL + k0 * 32 + quad * 8);
        #pragma unroll
        for (int j = 0; j < 8; j++) {
            qfH[k0][j] = f2bf(bf2f(rH[j]) * 0.125f);
            qfL[k0][j] = f2bf(bf2f(rL[j]) * 0.125f);
        }
    }

    f32x4 OaccH[4], OaccL[4];
    float psumH[4], psumL[4];
    #pragma unroll
    for (int nt = 0; nt < 4; nt++) {
        OaccH[nt] = (f32x4){0.f, 0.f, 0.f, 0.f};
        OaccL[nt] = (f32x4){0.f, 0.f, 0.f, 0.f};
    }
    #pragma unroll
    for (int r = 0; r < 4; r++) { psumH[r] = 0.f; psumL[r] = 0.f; }

    for (int jtk = 0; jtk <= qtH; jtk++) {
        __syncthreads();                       // prev-tile consumers done
        {
            const short* Ktile = Ktg + tb0 + (size_t)jtk * 4096;
            const short* Vtile = Vtg + tb0 + (size_t)jtk * 4096;
            #pragma unroll
            for (int i = 0; i < 2; i++) {
                const int ch = wave * 2 + i;   // 1KB chunks
                gload_lds16(Ktile + ch * 512 + lane * 8, &Ks[ch * 512]);
                gload_lds16(Vtile + ch * 512 + lane * 8, &Vs[ch * 512]);
            }
        }
        __syncthreads();                       // DMA drained by barrier

        const bool doL = (jtk <= qtL);

        // K fragments once, shared by both Q-tiles
        bf16x8 kf[8];
        #pragma unroll
        for (int nt = 0; nt < 4; nt++)
            #pragma unroll
            for (int k0 = 0; k0 < 2; k0++)
                kf[nt * 2 + k0] = *(const bf16x8*)
                    &Ks[(nt * 16 + l15) * 64 + (((k0 * 4 + quad) * 8) ^ lswz)];

        // S = (Q/8) K^T for hi (and lo)
        f32x4 sH[4], sL[4];
        #pragma unroll
        for (int nt = 0; nt < 4; nt++) {
            f32x4 a = {0.f, 0.f, 0.f, 0.f};
            a = __builtin_amdgcn_mfma_f32_16x16x32_bf16(qfH[0], kf[nt*2+0], a, 0, 0, 0);
            a = __builtin_amdgcn_mfma_f32_16x16x32_bf16(qfH[1], kf[nt*2+1], a, 0, 0, 0);
            sH[nt] = a;
        }
        if (doL) {
            #pragma unroll
            for (int nt = 0; nt < 4; nt++) {
                f32x4 a = {0.f, 0.f, 0.f, 0.f};
                a = __builtin_amdgcn_mfma_f32_16x16x32_bf16(qfL[0], kf[nt*2+0], a, 0, 0, 0);
                a = __builtin_amdgcn_mfma_f32_16x16x32_bf16(qfL[1], kf[nt*2+1], a, 0, 0, 0);
                sL[nt] = a;
            }
        }

        // fixed-shift softmax + ALiBi + causal; P -> wave-private LDS
        {
            const float relfH = (float)(jtk * 64 + l15 - quad * 4 - qrow0H);
            const bool mH = (jtk == qtH);
            #pragma unroll
            for (int nt = 0; nt < 4; nt++) {
                const int colsw = ((nt * 16 + l15) ^ wswz);
                #pragma unroll
                for (int r = 0; r < 4; r++) {
                    const float relv = relfH + (float)(nt * 16 - r);
                    float p = __expf(fmaf(slope, relv, sH[nt][r]));
                    if (mH && relv > 0.f) p = 0.f;
                    psumH[r] += p;
                    Pw[(quad * 4 + r) * LSTR + colsw] = f2bf(p);
                }
            }
        }
        if (doL) {
            const float relfL = (float)(jtk * 64 + l15 - quad * 4 - qrow0L);
            const bool mL = (jtk == qtL);
            #pragma unroll
            for (int nt = 0; nt < 4; nt++) {
                const int colsw = ((nt * 16 + l15) ^ wswz);
                #pragma unroll
                for (int r = 0; r < 4; r++) {
                    const float relv = relfL + (float)(nt * 16 - r);
                    float p = __expf(fmaf(slope, relv, sL[nt][r]));
                    if (mL && relv > 0.f) p = 0.f;
                    psumL[r] += p;
                    Pw[(16 + quad * 4 + r) * LSTR + colsw] = f2bf(p);
                }
            }
        }
        __asm__ volatile("s_waitcnt lgkmcnt(0)" ::: "memory");

        // V fragments once; O += P @ V for hi (and lo)
        bf16x8 vf[8];
        #pragma unroll
        for (int nt = 0; nt < 4; nt++)
            #pragma unroll
            for (int k0 = 0; k0 < 2; k0++)
                vf[nt * 2 + k0] = *(const bf16x8*)
                    &Vs[(nt * 16 + l15) * 64 + (((k0 * 4 + quad) * 8) ^ lswz)];

        {
            bf16x8 pf0 = *(const bf16x8*)&Pw[l15 * LSTR + ((quad * 8) ^ rswz)];
            bf16x8 pf1 = *(const bf16x8*)&Pw[l15 * LSTR + ((32 + quad * 8) ^ rswz)];
            #pragma unroll
            for (int nt = 0; nt < 4; nt++) {
                OaccH[nt] = __builtin_amdgcn_mfma_f32_16x16x32_bf16(
                    pf0, vf[nt*2+0], OaccH[nt], 0, 0, 0);
                OaccH[nt] = __builtin_amdgcn_mfma_f32_16x16x32_bf16(
                    pf1, vf[nt*2+1], OaccH[nt], 0, 0, 0);
            }
        }
        if (doL) {
            bf16x8 pf0 = *(const bf16x8*)&Pw[(16 + l15) * LSTR + ((quad * 8) ^ rswz)];
            bf16x8 pf1 = *(const bf16x8*)&Pw[(16 + l15) * LSTR + ((32 + quad * 8) ^ rswz)];
            #pragma unroll
            for (int nt = 0; nt < 4; nt++) {
                OaccL[nt] = __builtin_amdgcn_mfma_f32_16x16x32_bf16(
                    pf0, vf[nt*2+0], OaccL[nt], 0, 0, 0);
                OaccL[nt] = __builtin_amdgcn_mfma_f32_16x16x32_bf16(
                    pf1, vf[nt*2+1], OaccL[nt], 0, 0, 0);
            }
        }
    }

    // epilogue: reduce l across 16 key-lanes, normalize, store bf16
    #pragma unroll
    for (int r = 0; r < 4; r++) {
        const float invH = 1.f / dpp_sum16(psumH[r]);
        const float invL = 1.f / dpp_sum16(psumL[r]);
        const int rowH = qrow0H + quad * 4 + r;
        const int rowL = qrow0L + quad * 4 + r;
        short* ypH = Y + (bT + rowH) * C_ + h * 64 + l15;
        short* ypL = Y + (bT + rowL) * C_ + h * 64 + l15;
        #pragma unroll
        for (int nt = 0; nt < 4; nt++) {
            ypH[nt * 16] = f2bf(OaccH[nt][r] * invH);
            ypL[nt * 16] = f2bf(OaccL[nt][r] * invL);
        }
    }
}

extern "C" void kernel_launch(void* const* d_in, const int* in_sizes, int n_in,
                              void* d_out, int out_size, void* d_ws, size_t ws_size,
                              hipStream_t stream) {
    const float* x  = (const float*)d_in[0];
    const float* Wq = (const float*)d_in[1];
    const float* Wk = (const float*)d_in[2];
    const float* Wv = (const float*)d_in[3];
    const float* Wo = (const float*)d_in[4];
    float* out = (float*)d_out;

    const int M = B_ * T_;                           // 4096
    short* xb  = (short*)d_ws;                       // [4096][1024]
    short* Wt  = xb  + (size_t)M * C_;               // [1536][1024]
    short* Wot = Wt  + (size_t)NQKV_ * C_;           // [1024][1024]
    short* QKV = Wot + (size_t)C_ * C_;              // [4096][1536]
    short* Yb  = QKV + (size_t)M * NQKV_;            // [4096][1024]
    short* Ktg = Yb  + (size_t)M * C_;               // [8][32][4096] swizzled
    short* Vtg = Ktg + (size_t)8 * 32 * 4096;        // [8][32][4096] swizzled

    cast_bf16<<<dim3(M * C_ / (256 * 8)), dim3(256), 0, stream>>>(x, xb, M * C_);
    w_transpose<<<dim3(32, 32, 4), dim3(32, 8), 0, stream>>>(Wq, Wk, Wv, Wo, Wt, Wot);

    gemm_bf16<true><<<dim3(NQKV_ / 128, M / 64), dim3(256), 0, stream>>>(
        xb, Wt, QKV, M, NQKV_, C_);
    kv_tile<<<dim3(32, 8), dim3(256), 0, stream>>>(QKV, Ktg, Vtg);
    attn_mfma<<<dim3(NQT_ / 2, B_ * H_), dim3(256), 0, stream>>>(QKV, Ktg, Vtg, Yb);
    gemm_bf16<false><<<dim3(C_ / 128, M / 64), dim3(256), 0, stream>>>(
        Yb, Wot, out, M, C_, C_);
}

// Round 8
// 176.095 us; speedup vs baseline: 1.4359x; 1.0345x over previous
//
#include <hip/hip_runtime.h>
#include <hip/hip_bf16.h>
#include <math.h>

#define B_ 2
#define T_ 2048
#define C_ 1024
#define H_ 16
#define HKV_ 4
#define G_ 4
#define HD_ 64
#define KVC_ 256      // HKV*HD
#define NQKV_ 1536    // C_ + 2*KVC_
#define NQT_ 32       // T_/64 q-tiles

typedef __attribute__((ext_vector_type(8))) short bf16x8;
typedef __attribute__((ext_vector_type(4))) float f32x4;

static __device__ inline short f2bf(float f) {          // RNE (off hot path)
    __hip_bfloat16 h = __float2bfloat16(f);
    short s;
    __builtin_memcpy(&s, &h, 2);
    return s;
}
static __device__ inline short f2bf_trunc(float f) {    // RTZ, 1 op (hot path)
    unsigned int u;
    __builtin_memcpy(&u, &f, 4);
    return (short)(u >> 16);
}
static __device__ inline float bf2f(short s) {
    unsigned int u = ((unsigned int)(unsigned short)s) << 16;
    float f;
    __builtin_memcpy(&f, &u, 4);
    return f;
}

// async global->LDS, 16B per lane; lds base wave-uniform, dest = base + lane*16.
static __device__ inline void gload_lds16(const short* g, short* lds) {
    __builtin_amdgcn_global_load_lds(
        (const __attribute__((address_space(1))) unsigned int*)g,
        (__attribute__((address_space(3))) unsigned int*)lds, 16, 0, 0);
}

// ---------------- elementwise fp32 -> bf16 cast (8 elems/thread) ----------
__global__ __launch_bounds__(256) void cast_bf16(
    const float* __restrict__ in, short* __restrict__ out, int n)
{
    const int i = (blockIdx.x * 256 + threadIdx.x) * 8;
    if (i >= n) return;
    const float4 a = *(const float4*)(in + i);
    const float4 b = *(const float4*)(in + i + 4);
    bf16x8 o;
    o[0] = f2bf(a.x); o[1] = f2bf(a.y); o[2] = f2bf(a.z); o[3] = f2bf(a.w);
    o[4] = f2bf(b.x); o[5] = f2bf(b.y); o[6] = f2bf(b.z); o[7] = f2bf(b.w);
    *(bf16x8*)(out + i) = o;
}

// ------------- fused weight transpose+cast (z selects matrix) -------------
__global__ __launch_bounds__(256) void w_transpose(
    const float* __restrict__ Wq, const float* __restrict__ Wk,
    const float* __restrict__ Wv, const float* __restrict__ Wo,
    short* __restrict__ Wt, short* __restrict__ Wot)
{
    const int z = blockIdx.z;
    const float* in;
    short* out;
    int N;
    if (z == 0)      { in = Wq; out = Wt;                     N = C_; }
    else if (z == 1) { in = Wk; out = Wt + C_ * C_;           N = KVC_; }
    else if (z == 2) { in = Wv; out = Wt + (C_ + KVC_) * C_;  N = KVC_; }
    else             { in = Wo; out = Wot;                    N = C_; }
    const int n0 = blockIdx.x * 32;
    if (n0 >= N) return;
    __shared__ float t[32][33];
    const int tx = threadIdx.x, ty = threadIdx.y;     // 32 x 8
    const int k0 = blockIdx.y * 32;
    #pragma unroll
    for (int j = 0; j < 4; j++)
        t[ty + j * 8][tx] = in[(size_t)(k0 + ty + j * 8) * N + n0 + tx];
    __syncthreads();
    #pragma unroll
    for (int j = 0; j < 4; j++)
        out[(size_t)(n0 + ty + j * 8) * C_ + k0 + tx] = f2bf(t[tx][ty + j * 8]);
}

// ---------------- bf16 MFMA GEMM: 64x128 tile, BK=32 ----------------------
template <bool OUT_BF16>
__global__ __launch_bounds__(256) void gemm_bf16(
    const short* __restrict__ A, const short* __restrict__ Bt,
    void* __restrict__ Cout, int M, int N, int K)
{
    __shared__ short As[64 * 32];
    __shared__ short Bs[128 * 32];
    const int tid = threadIdx.x;
    const int wave = tid >> 6, lane = tid & 63;
    const int l15 = lane & 15, quad = lane >> 4;
    const int row0 = blockIdx.y * 64, col0 = blockIdx.x * 128;
    const int wrow = (wave >> 1) * 32, wcol = (wave & 1) * 64;

    f32x4 acc[2][4];
    #pragma unroll
    for (int i = 0; i < 2; i++)
        #pragma unroll
        for (int j = 0; j < 4; j++)
            acc[i][j] = (f32x4){0.f, 0.f, 0.f, 0.f};

    for (int kt = 0; kt < K; kt += 32) {
        __syncthreads();
        {
            const int r = wave * 16 + (lane >> 2);
            const int kof = (lane & 3) * 8;
            gload_lds16(A + (size_t)(row0 + r) * K + kt + kof, &As[wave * 512]);
        }
        #pragma unroll
        for (int c2 = 0; c2 < 2; c2++) {
            const int c = wave * 2 + c2;
            const int r = c * 16 + (lane >> 2);
            const int kof = (lane & 3) * 8;
            gload_lds16(Bt + (size_t)(col0 + r) * K + kt + kof, &Bs[c * 512]);
        }
        __syncthreads();

        bf16x8 af[2], bf[4];
        #pragma unroll
        for (int mt = 0; mt < 2; mt++)
            af[mt] = *(const bf16x8*)&As[(wrow + mt * 16 + l15) * 32 + quad * 8];
        #pragma unroll
        for (int nt = 0; nt < 4; nt++)
            bf[nt] = *(const bf16x8*)&Bs[(wcol + nt * 16 + l15) * 32 + quad * 8];
        #pragma unroll
        for (int mt = 0; mt < 2; mt++)
            #pragma unroll
            for (int nt = 0; nt < 4; nt++)
                acc[mt][nt] = __builtin_amdgcn_mfma_f32_16x16x32_bf16(
                    af[mt], bf[nt], acc[mt][nt], 0, 0, 0);
    }

    #pragma unroll
    for (int mt = 0; mt < 2; mt++) {
        #pragma unroll
        for (int r = 0; r < 4; r++) {
            const size_t row = row0 + wrow + mt * 16 + quad * 4 + r;
            #pragma unroll
            for (int nt = 0; nt < 4; nt++) {
                const size_t col = col0 + wcol + nt * 16 + l15;
                if (OUT_BF16)
                    ((short*)Cout)[row * N + col] = f2bf(acc[mt][nt][r]);
                else
                    ((float*)Cout)[row * N + col] = acc[mt][nt][r];
            }
        }
    }
}

// ---------------- K/V tiling prepass (XOR-swizzled 16B blocks) ------------
// K tile [key][dblk^(key&7)][8] ; V tile [d][kblk^(d&7)][8].
__global__ __launch_bounds__(256) void kv_tile(
    const short* __restrict__ QKV, short* __restrict__ Kt, short* __restrict__ Vt)
{
    __shared__ short Ls[64 * 72];
    const int jt = blockIdx.x;         // 0..31
    const int bk = blockIdx.y;         // 0..7 = b*4+kh
    const int b = bk >> 2, kh = bk & 3;
    const int tid = threadIdx.x;
    const int key = tid >> 2, d16 = (tid & 3) * 16;
    const size_t src = (size_t)(b * T_ + jt * 64 + key) * NQKV_ + C_ + kh * 64 + d16;
    const size_t tbase = (size_t)(bk * 32 + jt) * 4096;

    {   // K: swizzled tiled copy
        const int db0 = (tid & 3) * 2, db1 = db0 + 1;
        *(bf16x8*)(Kt + tbase + key * 64 + ((db0 ^ (key & 7)) * 8)) =
            *(const bf16x8*)(QKV + src);
        *(bf16x8*)(Kt + tbase + key * 64 + ((db1 ^ (key & 7)) * 8)) =
            *(const bf16x8*)(QKV + src + 8);
    }
    // V: transpose through LDS, swizzled key-blocks
    *(bf16x8*)&Ls[key * 72 + d16]     = *(const bf16x8*)(QKV + src + KVC_);
    *(bf16x8*)&Ls[key * 72 + d16 + 8] = *(const bf16x8*)(QKV + src + KVC_ + 8);
    __syncthreads();
    const int d = tid >> 2, k16 = (tid & 3) * 16;
    bf16x8 o0, o1;
    #pragma unroll
    for (int i = 0; i < 8; i++) o0[i] = Ls[(k16 + i) * 72 + d];
    #pragma unroll
    for (int i = 0; i < 8; i++) o1[i] = Ls[(k16 + 8 + i) * 72 + d];
    const int kb0 = (tid & 3) * 2, kb1 = kb0 + 1;
    *(bf16x8*)(Vt + tbase + d * 64 + ((kb0 ^ (d & 7)) * 8)) = o0;
    *(bf16x8*)(Vt + tbase + d * 64 + ((kb1 ^ (d & 7)) * 8)) = o1;
}

// ---------------- MFMA flash attention, work-balanced pairing -------------
// Block (qx,bh): Q-tiles qt_lo=qx, qt_hi=31-qx (constant 33 tiles/block).
// exp2-domain fixed-shift softmax (1/ln2 folded into Q cast + slope2);
// row-sums l via ones-MFMA (P @ 1) on the idle MFMA pipe; causal mask only
// on the (uniform) diagonal iteration; P cast = truncation (1 op).
#define LSTR 72

__global__ __launch_bounds__(256) void attn_mfma(
    const short* __restrict__ QKV, const short* __restrict__ Ktg,
    const short* __restrict__ Vtg, short* __restrict__ Y)
{
    const int qx = blockIdx.x;                 // 0..15
    const int bh = blockIdx.y;
    const int qtL = qx, qtH = NQT_ - 1 - qx;   // pair sums to 31
    const int b = bh >> 4, h = bh & 15, kh = h >> 2;
    const float slope2 = exp2f(-0.5f * (float)(kh + 1)) * 1.44269504f;
    const int tid = threadIdx.x;
    const int wave = tid >> 6, lane = tid & 63;
    const int l15 = lane & 15, quad = lane >> 4;
    const int lswz = (l15 & 7) * 8;            // K/V frag-read XOR (shorts)

    __shared__ short Ks[4096];                 // [key][dblk^(key&7)][8]
    __shared__ short Vs[4096];                 // [d][kblk^(d&7)][8]
    __shared__ short Ps[4 * 32 * LSTR];        // per wave: rows 0-15 hi, 16-31 lo
    short* Pw = &Ps[wave * 32 * LSTR];
    const int wswz = ((quad >> 1) & 1) << 4;   // P write XOR (row bit3)
    const int rswz = ((l15 >> 3) & 1) << 4;    // P read  XOR (row bit3)

    const size_t bT = (size_t)b * T_;
    const size_t tb0 = (size_t)((b * HKV_ + kh) * 32) * 4096;
    const int qrow0H = qtH * 64 + wave * 16;
    const int qrow0L = qtL * 64 + wave * 16;

    // Q fragments; scale 1/8 * 1/ln2 folded in (exp2-domain scores)
    const float qscale = 0.125f * 1.44269504f;
    bf16x8 qfH[2], qfL[2];
    #pragma unroll
    for (int k0 = 0; k0 < 2; k0++) {
        const short* qpH = QKV + (bT + qrow0H + l15) * NQKV_ + h * 64;
        const short* qpL = QKV + (bT + qrow0L + l15) * NQKV_ + h * 64;
        bf16x8 rH = *(const bf16x8*)(qpH + k0 * 32 + quad * 8);
        bf16x8 rL = *(const bf16x8*)(qpL + k0 * 32 + quad * 8);
        #pragma unroll
        for (int j = 0; j < 8; j++) {
            qfH[k0][j] = f2bf(bf2f(rH[j]) * qscale);
            qfL[k0][j] = f2bf(bf2f(rL[j]) * qscale);
        }
    }

    const short one_s = (short)0x3F80;         // bf16 1.0
    const bf16x8 ones = {one_s, one_s, one_s, one_s, one_s, one_s, one_s, one_s};

    f32x4 OaccH[4], OaccL[4], laccH, laccL;
    #pragma unroll
    for (int nt = 0; nt < 4; nt++) {
        OaccH[nt] = (f32x4){0.f, 0.f, 0.f, 0.f};
        OaccL[nt] = (f32x4){0.f, 0.f, 0.f, 0.f};
    }
    laccH = (f32x4){0.f, 0.f, 0.f, 0.f};
    laccL = (f32x4){0.f, 0.f, 0.f, 0.f};

    for (int jtk = 0; jtk <= qtH; jtk++) {
        __syncthreads();                       // prev-tile consumers done
        {
            const short* Ktile = Ktg + tb0 + (size_t)jtk * 4096;
            const short* Vtile = Vtg + tb0 + (size_t)jtk * 4096;
            #pragma unroll
            for (int i = 0; i < 2; i++) {
                const int ch = wave * 2 + i;   // 1KB chunks
                gload_lds16(Ktile + ch * 512 + lane * 8, &Ks[ch * 512]);
                gload_lds16(Vtile + ch * 512 + lane * 8, &Vs[ch * 512]);
            }
        }
        __syncthreads();                       // DMA drained by barrier

        const bool doL = (jtk <= qtL);

        // K fragments once, shared by both Q-tiles
        bf16x8 kf[8];
        #pragma unroll
        for (int nt = 0; nt < 4; nt++)
            #pragma unroll
            for (int k0 = 0; k0 < 2; k0++)
                kf[nt * 2 + k0] = *(const bf16x8*)
                    &Ks[(nt * 16 + l15) * 64 + (((k0 * 4 + quad) * 8) ^ lswz)];

        // S = (Q * qscale) K^T for hi (and lo)
        f32x4 sH[4], sL[4];
        #pragma unroll
        for (int nt = 0; nt < 4; nt++) {
            f32x4 a = {0.f, 0.f, 0.f, 0.f};
            a = __builtin_amdgcn_mfma_f32_16x16x32_bf16(qfH[0], kf[nt*2+0], a, 0, 0, 0);
            a = __builtin_amdgcn_mfma_f32_16x16x32_bf16(qfH[1], kf[nt*2+1], a, 0, 0, 0);
            sH[nt] = a;
        }
        if (doL) {
            #pragma unroll
            for (int nt = 0; nt < 4; nt++) {
                f32x4 a = {0.f, 0.f, 0.f, 0.f};
                a = __builtin_amdgcn_mfma_f32_16x16x32_bf16(qfL[0], kf[nt*2+0], a, 0, 0, 0);
                a = __builtin_amdgcn_mfma_f32_16x16x32_bf16(qfL[1], kf[nt*2+1], a, 0, 0, 0);
                sL[nt] = a;
            }
        }

        // exp2-domain softmax + ALiBi; mask only on diagonal tile (uniform)
        {
            const float base = slope2 * (float)(jtk * 64 + l15 - quad * 4 - qrow0H);
            if (jtk == qtH) {   // diagonal: apply causal mask
                #pragma unroll
                for (int nt = 0; nt < 4; nt++) {
                    const int colsw = ((nt * 16 + l15) ^ wswz);
                    #pragma unroll
                    for (int r = 0; r < 4; r++) {
                        const float relv = (float)(jtk * 64 + l15 - quad * 4 - qrow0H)
                                         + (float)(nt * 16 - r);
                        float p = __builtin_amdgcn_exp2f(
                            fmaf(slope2, (float)(nt * 16 - r), base) + sH[nt][r]);
                        if (relv > 0.f) p = 0.f;
                        Pw[(quad * 4 + r) * LSTR + colsw] = f2bf_trunc(p);
                    }
                }
            } else {            // clean path: add + exp + shr + write
                #pragma unroll
                for (int nt = 0; nt < 4; nt++) {
                    const int colsw = ((nt * 16 + l15) ^ wswz);
                    #pragma unroll
                    for (int r = 0; r < 4; r++) {
                        float p = __builtin_amdgcn_exp2f(
                            fmaf(slope2, (float)(nt * 16 - r), base) + sH[nt][r]);
                        Pw[(quad * 4 + r) * LSTR + colsw] = f2bf_trunc(p);
                    }
                }
            }
        }
        if (doL) {
            const float base = slope2 * (float)(jtk * 64 + l15 - quad * 4 - qrow0L);
            if (jtk == qtL) {
                #pragma unroll
                for (int nt = 0; nt < 4; nt++) {
                    const int colsw = ((nt * 16 + l15) ^ wswz);
                    #pragma unroll
                    for (int r = 0; r < 4; r++) {
                        const float relv = (float)(jtk * 64 + l15 - quad * 4 - qrow0L)
                                         + (float)(nt * 16 - r);
                        float p = __builtin_amdgcn_exp2f(
                            fmaf(slope2, (float)(nt * 16 - r), base) + sL[nt][r]);
                        if (relv > 0.f) p = 0.f;
                        Pw[(16 + quad * 4 + r) * LSTR + colsw] = f2bf_trunc(p);
                    }
                }
            } else {
                #pragma unroll
                for (int nt = 0; nt < 4; nt++) {
                    const int colsw = ((nt * 16 + l15) ^ wswz);
                    #pragma unroll
                    for (int r = 0; r < 4; r++) {
                        float p = __builtin_amdgcn_exp2f(
                            fmaf(slope2, (float)(nt * 16 - r), base) + sL[nt][r]);
                        Pw[(16 + quad * 4 + r) * LSTR + colsw] = f2bf_trunc(p);
                    }
                }
            }
        }
        __asm__ volatile("s_waitcnt lgkmcnt(0)" ::: "memory");

        // V fragments once; O += P @ V, l += P @ 1 (ones-MFMA row sums)
        bf16x8 vf[8];
        #pragma unroll
        for (int nt = 0; nt < 4; nt++)
            #pragma unroll
            for (int k0 = 0; k0 < 2; k0++)
                vf[nt * 2 + k0] = *(const bf16x8*)
                    &Vs[(nt * 16 + l15) * 64 + (((k0 * 4 + quad) * 8) ^ lswz)];

        {
            bf16x8 pf0 = *(const bf16x8*)&Pw[l15 * LSTR + ((quad * 8) ^ rswz)];
            bf16x8 pf1 = *(const bf16x8*)&Pw[l15 * LSTR + ((32 + quad * 8) ^ rswz)];
            laccH = __builtin_amdgcn_mfma_f32_16x16x32_bf16(pf0, ones, laccH, 0, 0, 0);
            laccH = __builtin_amdgcn_mfma_f32_16x16x32_bf16(pf1, ones, laccH, 0, 0, 0);
            #pragma unroll
            for (int nt = 0; nt < 4; nt++) {
                OaccH[nt] = __builtin_amdgcn_mfma_f32_16x16x32_bf16(
                    pf0, vf[nt*2+0], OaccH[nt], 0, 0, 0);
                OaccH[nt] = __builtin_amdgcn_mfma_f32_16x16x32_bf16(
                    pf1, vf[nt*2+1], OaccH[nt], 0, 0, 0);
            }
        }
        if (doL) {
            bf16x8 pf0 = *(const bf16x8*)&Pw[(16 + l15) * LSTR + ((quad * 8) ^ rswz)];
            bf16x8 pf1 = *(const bf16x8*)&Pw[(16 + l15) * LSTR + ((32 + quad * 8) ^ rswz)];
            laccL = __builtin_amdgcn_mfma_f32_16x16x32_bf16(pf0, ones, laccL, 0, 0, 0);
            laccL = __builtin_amdgcn_mfma_f32_16x16x32_bf16(pf1, ones, laccL, 0, 0, 0);
            #pragma unroll
            for (int nt = 0; nt < 4; nt++) {
                OaccL[nt] = __builtin_amdgcn_mfma_f32_16x16x32_bf16(
                    pf0, vf[nt*2+0], OaccL[nt], 0, 0, 0);
                OaccL[nt] = __builtin_amdgcn_mfma_f32_16x16x32_bf16(
                    pf1, vf[nt*2+1], OaccL[nt], 0, 0, 0);
            }
        }
    }

    // epilogue: l = lacc[r] (same in all 16 col-lanes), normalize, store bf16
    #pragma unroll
    for (int r = 0; r < 4; r++) {
        const float invH = 1.f / laccH[r];
        const float invL = 1.f / laccL[r];
        const int rowH = qrow0H + quad * 4 + r;
        const int rowL = qrow0L + quad * 4 + r;
        short* ypH = Y + (bT + rowH) * C_ + h * 64 + l15;
        short* ypL = Y + (bT + rowL) * C_ + h * 64 + l15;
        #pragma unroll
        for (int nt = 0; nt < 4; nt++) {
            ypH[nt * 16] = f2bf(OaccH[nt][r] * invH);
            ypL[nt * 16] = f2bf(OaccL[nt][r] * invL);
        }
    }
}

extern "C" void kernel_launch(void* const* d_in, const int* in_sizes, int n_in,
                              void* d_out, int out_size, void* d_ws, size_t ws_size,
                              hipStream_t stream) {
    const float* x  = (const float*)d_in[0];
    const float* Wq = (const float*)d_in[1];
    const float* Wk = (const float*)d_in[2];
    const float* Wv = (const float*)d_in[3];
    const float* Wo = (const float*)d_in[4];
    float* out = (float*)d_out;

    const int M = B_ * T_;                           // 4096
    short* xb  = (short*)d_ws;                       // [4096][1024]
    short* Wt  = xb  + (size_t)M * C_;               // [1536][1024]
    short* Wot = Wt  + (size_t)NQKV_ * C_;           // [1024][1024]
    short* QKV = Wot + (size_t)C_ * C_;              // [4096][1536]
    short* Yb  = QKV + (size_t)M * NQKV_;            // [4096][1024]
    short* Ktg = Yb  + (size_t)M * C_;               // [8][32][4096] swizzled
    short* Vtg = Ktg + (size_t)8 * 32 * 4096;        // [8][32][4096] swizzled

    cast_bf16<<<dim3(M * C_ / (256 * 8)), dim3(256), 0, stream>>>(x, xb, M * C_);
    w_transpose<<<dim3(32, 32, 4), dim3(32, 8), 0, stream>>>(Wq, Wk, Wv, Wo, Wt, Wot);

    gemm_bf16<true><<<dim3(NQKV_ / 128, M / 64), dim3(256), 0, stream>>>(
        xb, Wt, QKV, M, NQKV_, C_);
    kv_tile<<<dim3(32, 8), dim3(256), 0, stream>>>(QKV, Ktg, Vtg);
    attn_mfma<<<dim3(NQT_ / 2, B_ * H_), dim3(256), 0, stream>>>(QKV, Ktg, Vtg, Yb);
    gemm_bf16<false><<<dim3(C_ / 128, M / 64), dim3(256), 0, stream>>>(
        Yb, Wot, out, M, C_, C_);
}